// Round 2
// baseline (169.883 us; speedup 1.0000x reference)
//
#include <hip/hip_runtime.h>
#include <stdint.h>

typedef float f32x4_t __attribute__((ext_vector_type(4)));
typedef __bf16 bf16x8_t __attribute__((ext_vector_type(8)));

#define GLD16(gp, lp) __builtin_amdgcn_global_load_lds( \
    (const __attribute__((address_space(1))) void*)(gp), \
    (__attribute__((address_space(3))) void*)(lp), 16, 0, 0)

__device__ __forceinline__ uint32_t f2bf(float f) {
  uint32_t u = __float_as_uint(f);
  u += 0x7FFFu + ((u >> 16) & 1u);   // RNE; inputs are well-behaved (no NaN/Inf)
  return u >> 16;
}
__device__ __forceinline__ uint32_t pack2(float a, float b) {
  return f2bf(a) | (f2bf(b) << 16);
}

// ------------------------------------------------------------------
// build_w: W[(i1,i2,i3),(j1,j2,j3)] = sum_{r1,r2} c0[0,i1,j1,r1]*c1[r1,i2,j2,r2]*c2[r2,i3,j3,0]
// One block per (i1,j1) -> 256 blocks x 256 threads. W stored bf16 row-major (4096x4096).
// ------------------------------------------------------------------
__global__ __launch_bounds__(256) void build_w_kernel(
    const float* __restrict__ c0, const float* __restrict__ c1,
    const float* __restrict__ c2, uint16_t* __restrict__ W) {
  // M1[i2][j2][r2], i2-stride 516 (516 mod 32 = 4 -> the 4 distinct i2 per wave
  // hit distinct banks; 16 same-i2 lanes broadcast). 33 KB.
  __shared__ float M1[16 * 516];
  const int t = threadIdx.x;
  const int bid = blockIdx.x;
  const int i1 = bid >> 4, j1 = bid & 15;

  // Phase A: M1[i2,j2,r2] = sum_r1 c0[(i1*16+j1)*32+r1] * c1[r1*8192 + (i2*512+j2*32+r2)]
  const float* c0b = c0 + (i1 * 16 + j1) * 32;   // wave-uniform -> scalar loads
  const float4* c1v = (const float4*)c1;
  #pragma unroll 1
  for (int ee = 0; ee < 8; ++ee) {
    const int idx4 = t + 256 * ee;               // float4 index into the 8192-elem slab
    float ax = 0.f, ay = 0.f, az = 0.f, aw = 0.f;
    #pragma unroll 8
    for (int r1 = 0; r1 < 32; ++r1) {
      const float g = c0b[r1];
      const float4 v = c1v[r1 * 2048 + idx4];    // coalesced across threads
      ax += g * v.x; ay += g * v.y; az += g * v.z; aw += g * v.w;
    }
    const int idx = idx4 * 4;
    const int i2 = idx >> 9, j2 = (idx >> 5) & 15, r2 = idx & 31;  // r2 multiple of 4
    float* p = &M1[i2 * 516 + j2 * 32 + r2];
    p[0] = ax; p[1] = ay; p[2] = az; p[3] = aw;
  }
  __syncthreads();

  // Phase B/C: thread t -> (i2 = t>>4, i3 = t&16... (t&15)); computes W rows for its (i2,i3)
  // over all (j2,j3). g2 read directly from global (8 KB, L1-resident).
  const int i2 = t >> 4, i3 = t & 15;
  const int irow = (i1 * 16 + i2) * 16 + i3;
  uint16_t* Wr = W + (size_t)irow * 4096 + j1 * 256;
  const float4* c2v = (const float4*)c2;
  const float* M1b = &M1[i2 * 516];

  #pragma unroll 1
  for (int half = 0; half < 2; ++half) {          // j2 in [half*8, half*8+8)
    float acc[8][16];
    #pragma unroll
    for (int a = 0; a < 8; ++a)
      #pragma unroll
      for (int b = 0; b < 16; ++b) acc[a][b] = 0.f;

    const float* M1h = M1b + half * 8 * 32;
    #pragma unroll 4
    for (int r2 = 0; r2 < 32; ++r2) {
      const float4 q0 = c2v[r2 * 64 + i3 * 4 + 0];
      const float4 q1 = c2v[r2 * 64 + i3 * 4 + 1];
      const float4 q2 = c2v[r2 * 64 + i3 * 4 + 2];
      const float4 q3 = c2v[r2 * 64 + i3 * 4 + 3];
      float gv[16] = {q0.x, q0.y, q0.z, q0.w, q1.x, q1.y, q1.z, q1.w,
                      q2.x, q2.y, q2.z, q2.w, q3.x, q3.y, q3.z, q3.w};
      float m1v[8];
      #pragma unroll
      for (int jj = 0; jj < 8; ++jj) m1v[jj] = M1h[jj * 32 + r2];
      #pragma unroll
      for (int jj = 0; jj < 8; ++jj)
        #pragma unroll
        for (int j3 = 0; j3 < 16; ++j3)
          acc[jj][j3] += m1v[jj] * gv[j3];
    }
    // write 8 runs of 16 contiguous bf16 (32 B each)
    #pragma unroll
    for (int jj = 0; jj < 8; ++jj) {
      uint4 o0, o1;
      o0.x = pack2(acc[jj][0],  acc[jj][1]);  o0.y = pack2(acc[jj][2],  acc[jj][3]);
      o0.z = pack2(acc[jj][4],  acc[jj][5]);  o0.w = pack2(acc[jj][6],  acc[jj][7]);
      o1.x = pack2(acc[jj][8],  acc[jj][9]);  o1.y = pack2(acc[jj][10], acc[jj][11]);
      o1.z = pack2(acc[jj][12], acc[jj][13]); o1.w = pack2(acc[jj][14], acc[jj][15]);
      uint4* dst = (uint4*)(Wr + half * 128 + jj * 16);
      dst[0] = o0; dst[1] = o1;
    }
  }
}

// ------------------------------------------------------------------
// cvt_x: fp32 -> bf16, 8 elems/thread, vectorized
// ------------------------------------------------------------------
__global__ __launch_bounds__(256) void cvt_x_kernel(const float* __restrict__ x,
                                                    uint32_t* __restrict__ xb) {
  const int i = blockIdx.x * 256 + threadIdx.x;   // 524288 threads total
  const float4* x4 = (const float4*)x;
  const float4 a = x4[2 * i], b = x4[2 * i + 1];
  uint4 o;
  o.x = pack2(a.x, a.y); o.y = pack2(a.z, a.w);
  o.z = pack2(b.x, b.y); o.w = pack2(b.z, b.w);
  ((uint4*)xb)[i] = o;
}

// ------------------------------------------------------------------
// GEMM: C[1024,4096] = A[1024,4096](bf16) * Bt[4096,4096]^T (bf16, (n,k) layout) + bias
// BM=64 BN=128 BK=64, 256 thr (4 waves, wave tile 32x64), 512 blocks = 2/CU.
// global_load_lds w=16 staging; XOR-swizzled LDS (pre-swizzled global source,
// swizzled ds_read — both-sides rule) to kill the 16-way bank conflict of
// linear [row][64] layout.
// ------------------------------------------------------------------
__global__ __launch_bounds__(256, 2) void gemm_bt_bias_kernel(
    const uint16_t* __restrict__ A, const uint16_t* __restrict__ Bt,
    const float* __restrict__ bias, float* __restrict__ C) {
  constexpr int Kd = 4096, Nd = 4096;
  __shared__ uint16_t As[64 * 64];    // 8 KB
  __shared__ uint16_t Bs[128 * 64];   // 16 KB
  const int t = threadIdx.x;
  const int wid = t >> 6, lane = t & 63;

  // XCD-grouped mapping: XCD g owns n-tiles [4g, 4g+4) x all 16 m-tiles
  const int bid = blockIdx.x;
  const int g = bid & 7, idx = bid >> 3;
  const int ntile = g * 4 + (idx >> 4);   // 0..31
  const int mtile = idx & 15;             // 0..15
  const int brow = mtile * 64, bcol = ntile * 128;

  const uint16_t* Ab = A + (size_t)brow * Kd;
  const uint16_t* Bb = Bt + (size_t)bcol * Kd;

  // staging: thread t covers tile row rb = t>>3, 16B chunk (t&7); source column
  // pre-swizzled so linear LDS + swizzled read agree (involution: xor (row&7)<<3 elems)
  const int rb = t >> 3;                                  // 0..31
  const int ce = ((t & 7) * 8) ^ ((rb & 7) << 3);         // element offset in row
  const uint16_t* gA = Ab + (size_t)rb * Kd + ce;
  const uint16_t* gB = Bb + (size_t)rb * Kd + ce;
  uint16_t* lA0 = As + wid * 512;
  uint16_t* lA1 = As + 2048 + wid * 512;
  uint16_t* lB0 = Bs + wid * 512;
  uint16_t* lB1 = Bs + 2048 + wid * 512;
  uint16_t* lB2 = Bs + 4096 + wid * 512;
  uint16_t* lB3 = Bs + 6144 + wid * 512;

  const int wm = wid >> 1, wn = wid & 1;                  // wave tile (wm*32, wn*64)
  const int fr = lane & 15, fk = (lane >> 4) * 8;
  const int csw = (fr & 7) << 3;                          // read-side swizzle

  f32x4_t zero = {0.f, 0.f, 0.f, 0.f};
  f32x4_t acc[2][4];
  #pragma unroll
  for (int m = 0; m < 2; ++m)
    #pragma unroll
    for (int n = 0; n < 4; ++n) acc[m][n] = zero;

  for (int kt = 0; kt < Kd; kt += 64) {
    GLD16(gA + kt, lA0);
    GLD16(gA + (size_t)32 * Kd + kt, lA1);
    GLD16(gB + kt, lB0);
    GLD16(gB + (size_t)32 * Kd + kt, lB1);
    GLD16(gB + (size_t)64 * Kd + kt, lB2);
    GLD16(gB + (size_t)96 * Kd + kt, lB3);
    __syncthreads();   // compiler drains vmcnt(0) here -> staged data visible

    bf16x8_t af[2][2], bfr[2][4];
    #pragma unroll
    for (int kk = 0; kk < 2; ++kk) {
      const int col = (kk * 32 + fk) ^ csw;
      #pragma unroll
      for (int m = 0; m < 2; ++m)
        af[kk][m] = *(const bf16x8_t*)(As + (wm * 32 + m * 16 + fr) * 64 + col);
      #pragma unroll
      for (int n = 0; n < 4; ++n)
        bfr[kk][n] = *(const bf16x8_t*)(Bs + (wn * 64 + n * 16 + fr) * 64 + col);
    }
    #pragma unroll
    for (int kk = 0; kk < 2; ++kk)
      #pragma unroll
      for (int m = 0; m < 2; ++m)
        #pragma unroll
        for (int n = 0; n < 4; ++n)
          acc[m][n] = __builtin_amdgcn_mfma_f32_16x16x32_bf16(
              af[kk][m], bfr[kk][n], acc[m][n], 0, 0, 0);
    __syncthreads();   // protect LDS before next stage
  }

  // epilogue: C/D layout col=lane&15, row=(lane>>4)*4+reg (m89/m91)
  const int orow = brow + wm * 32 + (lane >> 4) * 4;
  const int ocol = bcol + wn * 64 + fr;
  #pragma unroll
  for (int n = 0; n < 4; ++n) {
    const float bv = bias[ocol + n * 16];
    #pragma unroll
    for (int m = 0; m < 2; ++m) {
      float* Cp = C + (size_t)(orow + m * 16) * Nd + ocol + n * 16;
      #pragma unroll
      for (int r = 0; r < 4; ++r) Cp[(size_t)r * Nd] = acc[m][n][r] + bv;
    }
  }
}

extern "C" void kernel_launch(void* const* d_in, const int* in_sizes, int n_in,
                              void* d_out, int out_size, void* d_ws, size_t ws_size,
                              hipStream_t stream) {
  const float* x    = (const float*)d_in[0];   // (1024, 4096)
  const float* c0   = (const float*)d_in[1];   // (1, 16, 16, 32)
  const float* c1   = (const float*)d_in[2];   // (32, 16, 16, 32)
  const float* c2   = (const float*)d_in[3];   // (32, 16, 16, 1)
  const float* bias = (const float*)d_in[4];   // (4096,)
  float* y = (float*)d_out;                    // (1024, 4096)

  // workspace: W bf16 (32 MB) + xb bf16 (8 MB)  => needs ~40 MB of d_ws
  uint16_t* W  = (uint16_t*)d_ws;
  uint16_t* xb = (uint16_t*)d_ws + (size_t)4096 * 4096;

  build_w_kernel<<<256, 256, 0, stream>>>(c0, c1, c2, W);
  cvt_x_kernel<<<2048, 256, 0, stream>>>(x, (uint32_t*)xb);
  gemm_bt_bias_kernel<<<512, 256, 0, stream>>>(xb, W, bias, y);
}